// Round 1
// baseline (515.475 us; speedup 1.0000x reference)
//
#include <hip/hip_runtime.h>

#define T_TOK 2048
#define HID   2048
#define INTER 768
#define NE    32
#define NSLOT 8192   // T_TOK * TOP_K

typedef short bf16x8 __attribute__((ext_vector_type(8)));
typedef float f32x4  __attribute__((ext_vector_type(4)));

__device__ __forceinline__ unsigned short f2b(float f){
  unsigned u = __builtin_bit_cast(unsigned, f);
  u += 0x7fffu + ((u >> 16) & 1u);      // RNE
  return (unsigned short)(u >> 16);
}

// ---------------- workspace layout (bytes) ----------------
#define XB_OFF    0ul           // bf16 x  [2048][2048]  = 8388608
#define HBUF_OFF  8388608ul     // bf16 h  [8192][768]   = 12582912
#define TKW_OFF   20971520ul    // f32 topk_w [2048][4]  = 32768
#define TKI_OFF   21004288ul    // i32 topk_i [2048][4]  = 32768
#define ROWS_OFF  21037056ul    // i32 rows [8192]       = 32768
#define WTS_OFF   21069824ul    // f32 wts  [8192]       = 32768
#define OFFS_OFF  21102592ul    // i32 offsets[33] (256B)
#define LOGIT_OFF 21102848ul    // f32 logits [2048][32] = 262144  (zeroed)
#define CNT_OFF   21364992ul    // i32 counts[32]        (zeroed)
#define FILL_OFF  21365120ul    // i32 fill[32]          (zeroed)
#define ZERO_OFF  21102848ul
#define ZERO_SZ   (262144ul + 128ul + 128ul)

// ---------------- x fp32 -> bf16 ----------------
__global__ void convert_x_kernel(const float* __restrict__ x, ushort* __restrict__ xb){
  int i = (blockIdx.x * 256 + threadIdx.x) * 8;
  float4 a = *(const float4*)(x + i);
  float4 b = *(const float4*)(x + i + 4);
  uint4 o;
  o.x = f2b(a.x) | ((unsigned)f2b(a.y) << 16);
  o.y = f2b(a.z) | ((unsigned)f2b(a.w) << 16);
  o.z = f2b(b.x) | ((unsigned)f2b(b.y) << 16);
  o.w = f2b(b.z) | ((unsigned)f2b(b.w) << 16);
  *(uint4*)(xb + i) = o;
}

// ---------------- router logits (fp32 GEMM, split-K atomic) ----------------
// grid (32 token-tiles, 8 k-splits), 256 threads
__global__ void router_gemm(const float* __restrict__ x, const float* __restrict__ wr,
                            float* __restrict__ logits){
  const int tt = blockIdx.x;   // 64 tokens
  const int kb = blockIdx.y;   // 256 k
  __shared__ float xs[64 * 64];
  __shared__ float wsm[64 * 32];
  const int tid = threadIdx.x;
  const int r = tid >> 5, e = tid & 31;
  float acc[8];
#pragma unroll
  for (int i = 0; i < 8; i++) acc[i] = 0.0f;

  for (int sub = 0; sub < 4; ++sub){
    const int k0 = kb * 256 + sub * 64;
    __syncthreads();
#pragma unroll
    for (int j = 0; j < 4; j++){
      int f4 = tid + j * 256;
      int row = f4 >> 4, c4 = f4 & 15;
      float4 v = *(const float4*)(x + (size_t)(tt * 64 + row) * HID + k0 + c4 * 4);
      *(float4*)(xs + row * 64 + c4 * 4) = v;
    }
#pragma unroll
    for (int j = 0; j < 2; j++){
      int f4 = tid + j * 256;
      int row = f4 >> 3, c4 = f4 & 7;
      float4 v = *(const float4*)(wr + (size_t)(k0 + row) * NE + c4 * 4);
      *(float4*)(wsm + row * NE + c4 * 4) = v;
    }
    __syncthreads();
    for (int kk = 0; kk < 64; kk++){
      float wv = wsm[kk * NE + e];
#pragma unroll
      for (int i = 0; i < 8; i++) acc[i] += xs[(r + i * 8) * 64 + kk] * wv;
    }
  }
#pragma unroll
  for (int i = 0; i < 8; i++)
    atomicAdd(&logits[(size_t)(tt * 64 + r + i * 8) * NE + e], acc[i]);
}

// ---------------- softmax + top-4 + renorm + counts ----------------
__global__ void topk_kernel(const float* __restrict__ logits, float* __restrict__ topk_w,
                            int* __restrict__ topk_i, int* __restrict__ counts){
  int t = blockIdx.x * blockDim.x + threadIdx.x;
  if (t >= T_TOK) return;
  float l[32];
  const float4* lp = (const float4*)(logits + (size_t)t * NE);
#pragma unroll
  for (int i = 0; i < 8; i++){
    float4 v = lp[i];
    l[i*4+0] = v.x; l[i*4+1] = v.y; l[i*4+2] = v.z; l[i*4+3] = v.w;
  }
  float m = l[0];
#pragma unroll
  for (int i = 1; i < 32; i++) m = fmaxf(m, l[i]);
#pragma unroll
  for (int i = 0; i < 32; i++) l[i] = __expf(l[i] - m);   // softmax denom cancels in renorm
  float wsel[4]; int isel[4];
#pragma unroll
  for (int k = 0; k < 4; k++){
    float best = l[0]; int bi = 0;
#pragma unroll
    for (int i = 1; i < 32; i++){ if (l[i] > best){ best = l[i]; bi = i; } }
    wsel[k] = best; isel[k] = bi; l[bi] = -1.0f;
  }
  float s4 = wsel[0] + wsel[1] + wsel[2] + wsel[3];
  float inv = 1.0f / s4;
#pragma unroll
  for (int k = 0; k < 4; k++){
    topk_w[t * 4 + k] = wsel[k] * inv;
    topk_i[t * 4 + k] = isel[k];
    atomicAdd(&counts[isel[k]], 1);
  }
}

__global__ void prefix_kernel(const int* __restrict__ counts, int* __restrict__ offsets){
  if (threadIdx.x == 0){
    int a = 0; offsets[0] = 0;
    for (int e = 0; e < NE; e++){ a += counts[e]; offsets[e + 1] = a; }
  }
}

__global__ void scatter_kernel(const int* __restrict__ topk_i, const float* __restrict__ topk_w,
                               const int* __restrict__ offsets, int* __restrict__ fill,
                               int* __restrict__ rows, float* __restrict__ wts){
  int gid = blockIdx.x * 256 + threadIdx.x;   // 0..8191
  int t = gid >> 2;
  int e = topk_i[gid];
  int pos = atomicAdd(&fill[e], 1);
  int s = offsets[e] + pos;
  rows[s] = t;
  wts[s] = topk_w[gid];
}

// ---------------- gate+up GEMM: h = silu(x@wg)*(x@wu) * wt, bf16 ----------------
// grid (12 n-tiles, 8 m-tiles, 32 experts), 512 threads. BM=256 BN=64 BK=32.
__global__ __launch_bounds__(512, 1) void gateup_kernel(
    const ushort* __restrict__ xb, const float* __restrict__ wg,
    const float* __restrict__ wu, const int* __restrict__ rows,
    const float* __restrict__ wts, const int* __restrict__ counts,
    const int* __restrict__ offsets, ushort* __restrict__ hbuf)
{
  const int e = blockIdx.z, mt = blockIdx.y, nt = blockIdx.x;
  const int cnt = counts[e];
  if (mt * 256 >= cnt) return;
  const int off = offsets[e];
  const int n0 = nt * 64;

  __shared__ __align__(16) ushort Asm[256 * 40];
  __shared__ __align__(16) ushort Bg[64 * 40];
  __shared__ __align__(16) ushort Bu[64 * 40];
  __shared__ int   tokid[256];
  __shared__ float wrow[256];

  const int tid = threadIdx.x;
  if (tid < 256){
    int valid = (mt * 256 + tid) < cnt;
    int s = valid ? (off + mt * 256 + tid) : off;
    tokid[tid] = rows[s];
    wrow[tid] = valid ? wts[s] : 0.0f;
  }
  __syncthreads();

  // A staging: 2 units of 8 bf16 per thread
  const int r0 = tid >> 2, r1 = r0 + 128, quad = tid & 3;
  const ushort* asrc0 = xb + (size_t)tokid[r0] * HID + quad * 8;
  const ushort* asrc1 = xb + (size_t)tokid[r1] * HID + quad * 8;
  ushort* adst0 = Asm + r0 * 40 + quad * 8;
  ushort* adst1 = Asm + r1 * 40 + quad * 8;

  // B staging: lane-per-column, 4 k per thread per matrix
  const int bn = tid & 63, kg = tid >> 6;
  const float* wgp = wg + (size_t)e * HID * INTER + (size_t)kg * 4 * INTER + n0 + bn;
  const float* wup = wu + (size_t)e * HID * INTER + (size_t)kg * 4 * INTER + n0 + bn;
  ushort* bgdst = Bg + bn * 40 + kg * 4;
  ushort* budst = Bu + bn * 40 + kg * 4;

  const int lane = tid & 63, wv = tid >> 6;
  const int wm = wv >> 1, wn = wv & 1;
  const int fr = lane & 15, ko = lane >> 4;
  const ushort* aread  = Asm + (size_t)(wm * 64 + fr) * 40 + ko * 8;
  const ushort* bgread = Bg  + (size_t)(wn * 32 + fr) * 40 + ko * 8;
  const ushort* buread = Bu  + (size_t)(wn * 32 + fr) * 40 + ko * 8;

  f32x4 accg[4][2], accu[4][2];
#pragma unroll
  for (int i = 0; i < 4; i++)
#pragma unroll
    for (int j = 0; j < 2; j++){ accg[i][j] = (f32x4)(0.0f); accu[i][j] = (f32x4)(0.0f); }

  for (int k0 = 0; k0 < HID; k0 += 32){
    __syncthreads();
    *(uint4*)adst0 = *(const uint4*)(asrc0 + k0);
    *(uint4*)adst1 = *(const uint4*)(asrc1 + k0);
    {
      const float* p = wgp + (size_t)k0 * INTER;
      float v0 = p[0], v1 = p[INTER], v2 = p[2 * INTER], v3 = p[3 * INTER];
      uint2 o; o.x = f2b(v0) | ((unsigned)f2b(v1) << 16);
               o.y = f2b(v2) | ((unsigned)f2b(v3) << 16);
      *(uint2*)bgdst = o;
      const float* q = wup + (size_t)k0 * INTER;
      v0 = q[0]; v1 = q[INTER]; v2 = q[2 * INTER]; v3 = q[3 * INTER];
      o.x = f2b(v0) | ((unsigned)f2b(v1) << 16);
      o.y = f2b(v2) | ((unsigned)f2b(v3) << 16);
      *(uint2*)budst = o;
    }
    __syncthreads();
    bf16x8 a[4], bg2[2], bu2[2];
#pragma unroll
    for (int mf = 0; mf < 4; mf++) a[mf] = *(const bf16x8*)(aread + mf * 16 * 40);
#pragma unroll
    for (int nf = 0; nf < 2; nf++){
      bg2[nf] = *(const bf16x8*)(bgread + nf * 16 * 40);
      bu2[nf] = *(const bf16x8*)(buread + nf * 16 * 40);
    }
#pragma unroll
    for (int mf = 0; mf < 4; mf++)
#pragma unroll
      for (int nf = 0; nf < 2; nf++){
        accg[mf][nf] = __builtin_amdgcn_mfma_f32_16x16x32_bf16(a[mf], bg2[nf], accg[mf][nf], 0, 0, 0);
        accu[mf][nf] = __builtin_amdgcn_mfma_f32_16x16x32_bf16(a[mf], bu2[nf], accu[mf][nf], 0, 0, 0);
      }
  }

#pragma unroll
  for (int mf = 0; mf < 4; mf++)
#pragma unroll
    for (int nf = 0; nf < 2; nf++)
#pragma unroll
      for (int j = 0; j < 4; j++){
        int rl = wm * 64 + mf * 16 + ko * 4 + j;
        if (mt * 256 + rl < cnt){
          int col = wn * 32 + nf * 16 + fr;
          float g = accg[mf][nf][j], u = accu[mf][nf][j];
          float h = (g / (1.0f + __expf(-g))) * u * wrow[rl];
          hbuf[(size_t)(off + mt * 256 + rl) * INTER + n0 + col] = f2b(h);
        }
      }
}

// ---------------- down GEMM: out[tok] += h @ wd ----------------
// grid (32 n-tiles, 8 m-tiles, 32 experts), 512 threads. BM=256 BN=64 BK=32, K=768.
__global__ __launch_bounds__(512, 1) void down_kernel(
    const ushort* __restrict__ hbuf, const float* __restrict__ wd,
    const int* __restrict__ rows, const int* __restrict__ counts,
    const int* __restrict__ offsets, float* __restrict__ out)
{
  const int e = blockIdx.z, mt = blockIdx.y, nt = blockIdx.x;
  const int cnt = counts[e];
  if (mt * 256 >= cnt) return;
  const int off = offsets[e];
  const int n0 = nt * 64;

  __shared__ __align__(16) ushort Asm[256 * 40];
  __shared__ __align__(16) ushort Bd[64 * 40];
  __shared__ int tokid[256];

  const int tid = threadIdx.x;
  if (tid < 256){
    int s = off + mt * 256 + tid;
    tokid[tid] = rows[min(s, NSLOT - 1)];
  }
  __syncthreads();

  const int r0 = tid >> 2, r1 = r0 + 128, quad = tid & 3;
  int s0 = min(off + mt * 256 + r0, NSLOT - 1);
  int s1 = min(off + mt * 256 + r1, NSLOT - 1);
  const ushort* asrc0 = hbuf + (size_t)s0 * INTER + quad * 8;
  const ushort* asrc1 = hbuf + (size_t)s1 * INTER + quad * 8;
  ushort* adst0 = Asm + r0 * 40 + quad * 8;
  ushort* adst1 = Asm + r1 * 40 + quad * 8;

  const int bn = tid & 63, kg = tid >> 6;
  const float* wdp = wd + (size_t)e * INTER * HID + (size_t)kg * 4 * HID + n0 + bn;
  ushort* bdst = Bd + bn * 40 + kg * 4;

  const int lane = tid & 63, wv = tid >> 6;
  const int wm = wv >> 1, wn = wv & 1;
  const int fr = lane & 15, ko = lane >> 4;
  const ushort* aread = Asm + (size_t)(wm * 64 + fr) * 40 + ko * 8;
  const ushort* bread = Bd  + (size_t)(wn * 32 + fr) * 40 + ko * 8;

  f32x4 acc[4][2];
#pragma unroll
  for (int i = 0; i < 4; i++)
#pragma unroll
    for (int j = 0; j < 2; j++) acc[i][j] = (f32x4)(0.0f);

  for (int k0 = 0; k0 < INTER; k0 += 32){
    __syncthreads();
    *(uint4*)adst0 = *(const uint4*)(asrc0 + k0);
    *(uint4*)adst1 = *(const uint4*)(asrc1 + k0);
    {
      const float* p = wdp + (size_t)k0 * HID;
      float v0 = p[0], v1 = p[HID], v2 = p[2 * HID], v3 = p[3 * HID];
      uint2 o; o.x = f2b(v0) | ((unsigned)f2b(v1) << 16);
               o.y = f2b(v2) | ((unsigned)f2b(v3) << 16);
      *(uint2*)bdst = o;
    }
    __syncthreads();
    bf16x8 a[4], b2[2];
#pragma unroll
    for (int mf = 0; mf < 4; mf++) a[mf] = *(const bf16x8*)(aread + mf * 16 * 40);
#pragma unroll
    for (int nf = 0; nf < 2; nf++) b2[nf] = *(const bf16x8*)(bread + nf * 16 * 40);
#pragma unroll
    for (int mf = 0; mf < 4; mf++)
#pragma unroll
      for (int nf = 0; nf < 2; nf++)
        acc[mf][nf] = __builtin_amdgcn_mfma_f32_16x16x32_bf16(a[mf], b2[nf], acc[mf][nf], 0, 0, 0);
  }

#pragma unroll
  for (int mf = 0; mf < 4; mf++)
#pragma unroll
    for (int nf = 0; nf < 2; nf++)
#pragma unroll
      for (int j = 0; j < 4; j++){
        int rl = wm * 64 + mf * 16 + ko * 4 + j;
        if (mt * 256 + rl < cnt){
          int col = wn * 32 + nf * 16 + fr;
          atomicAdd(&out[(size_t)tokid[rl] * HID + n0 + col], acc[mf][nf][j]);
        }
      }
}

// ---------------- launch ----------------
extern "C" void kernel_launch(void* const* d_in, const int* in_sizes, int n_in,
                              void* d_out, int out_size, void* d_ws, size_t ws_size,
                              hipStream_t stream){
  const float* x  = (const float*)d_in[0];
  const float* wr = (const float*)d_in[1];
  const float* wg = (const float*)d_in[2];
  const float* wu = (const float*)d_in[3];
  const float* wd = (const float*)d_in[4];
  float* out = (float*)d_out;
  char* ws = (char*)d_ws;

  ushort* xb     = (ushort*)(ws + XB_OFF);
  ushort* hbuf   = (ushort*)(ws + HBUF_OFF);
  float*  topkw  = (float*)(ws + TKW_OFF);
  int*    topki  = (int*)(ws + TKI_OFF);
  int*    rows   = (int*)(ws + ROWS_OFF);
  float*  wts    = (float*)(ws + WTS_OFF);
  int*    offs   = (int*)(ws + OFFS_OFF);
  float*  logits = (float*)(ws + LOGIT_OFF);
  int*    counts = (int*)(ws + CNT_OFF);
  int*    fill   = (int*)(ws + FILL_OFF);

  hipMemsetAsync(ws + ZERO_OFF, 0, ZERO_SZ, stream);
  hipMemsetAsync(d_out, 0, (size_t)out_size * sizeof(float), stream);

  convert_x_kernel<<<2048, 256, 0, stream>>>(x, xb);
  router_gemm<<<dim3(32, 8), 256, 0, stream>>>(x, wr, logits);
  topk_kernel<<<8, 256, 0, stream>>>(logits, topkw, topki, counts);
  prefix_kernel<<<1, 64, 0, stream>>>(counts, offs);
  scatter_kernel<<<32, 256, 0, stream>>>(topki, topkw, offs, fill, rows, wts);
  gateup_kernel<<<dim3(12, 8, 32), 512, 0, stream>>>(xb, wg, wu, rows, wts, counts, offs, hbuf);
  down_kernel<<<dim3(32, 8, 32), 512, 0, stream>>>(hbuf, wd, rows, counts, offs, out);
}